// Round 4
// baseline (149.629 us; speedup 1.0000x reference)
//
#include <hip/hip_runtime.h>
#include <hip/hip_bf16.h>

// HybridLoss: focal + contrastive + 0.1*graph_reg.  N=8192, D=128.
// v4: amortize per-workgroup overhead.  v3 post-mortem: 2368 tiny blocks at
// ~18 ns/block of dispatch/setup overhead = 43.5 us main_kernel with VALUBusy
// 15.6% / occupancy 16% (and _ord 0 showed identical duration at 0.3% VALU:
// duration invariant to work => per-block overhead bound, not pipe bound).
// v4: 360 blocks total, grid-strided (260 pair x 8 tiles, 32 prep x 4 chunks,
// 4 focal x 2048, 64 graph x 128 rows); prep fused into main (its outputs are
// consumed only by finalize); 2 launches instead of 3 (~10 us/boundary).
// Cross-block dataflow stays plain-store + kernel-boundary coherence
// (no atomics/fences -- v2's single-address rendezvous cost ~27ns/block).
//  - pair tiles SELF-CONTAINED: screen fragments (dims 0..31) in-register
//    from f32 features; bound sq32 = s32_i + s32_j - 2*dot32; slow path
//    (full K=128 gram + exact f32 row norms) only if wave-min < 2.
//  - same-label pairs: closed form 2*n_c*S_c - 2*||sum_c f||^2 in finalize.

#define N_PTS 8192
#define DIM 128

typedef __bf16 bf16x8 __attribute__((ext_vector_type(8)));
typedef float f32x4 __attribute__((ext_vector_type(4)));

// grid partition (main_kernel)
#define G_PAIR 260          // x8 tiles = 2080 upper-tri 128x128 tiles
#define G_PREP 32           // x4 chunks = 128 column-sum chunks
#define G_FOCAL 4           // x2048 elements
#define G_GRAPH 64          // x128 rows
#define NMAIN (G_PAIR + G_PREP + G_FOCAL + G_GRAPH)

// workspace layout (bytes)
#define VPART_OFF 0                      // float[128][256] col sums (cls0 | cls1)
#define SPART_OFF 131072                 // float4[128] : {ssq_all, ssq_cls1, n1, 0}
#define CPART_OFF 133120                 // float[260*4] pair per-wave partials
#define FPART_OFF 137280                 // float[4*4]   focal per-wave partials
#define GPART_OFF 137344                 // float[64*4]  graph per-wave partials

__device__ __forceinline__ bf16x8 pack8(const float4 a, const float4 b) {
    bf16x8 r;
    r[0] = (__bf16)a.x; r[1] = (__bf16)a.y; r[2] = (__bf16)a.z; r[3] = (__bf16)a.w;
    r[4] = (__bf16)b.x; r[5] = (__bf16)b.y; r[6] = (__bf16)b.z; r[7] = (__bf16)b.w;
    return r;
}
__device__ __forceinline__ float ssq8(const float4 a, const float4 b) {
    return a.x * a.x + a.y * a.y + a.z * a.z + a.w * a.w
         + b.x * b.x + b.y * b.y + b.z * b.z + b.w * b.w;
}

// ================= slow-path scan (unchanged, verified v1-v3) ==================
template<bool DIAG>
__device__ __forceinline__ float scan_slow(const f32x4 (&acc)[4][4],
                                           const f32x4 (&sqni)[4], const f32x4 (&ti4)[4],
                                           const float (&sqnj)[4], const float (&tj4)[4],
                                           int wm, int wn, int quad, int m15) {
    float lsum = 0.f;
    #pragma unroll
    for (int tm = 0; tm < 4; ++tm) {
        #pragma unroll
        for (int tn = 0; tn < 4; ++tn) {
            const int jl = wn * 64 + tn * 16 + m15;
            #pragma unroll
            for (int e = 0; e < 4; ++e) {
                const float sq = sqni[tm][e] + sqnj[tn] - 2.f * acc[tm][tn][e];
                bool excl = (ti4[tm][e] == tj4[tn]);
                if (DIAG) {
                    const int il = wm * 64 + tm * 16 + quad * 4 + e;
                    excl = excl || (jl <= il);
                }
                if (!excl && sq < 1.f) {
                    const float d = sqrtf(fmaxf(sq, 0.f));
                    const float m = 1.f - d;
                    lsum += 2.f * m * m;
                }
            }
        }
    }
    return lsum;
}

// ====== launch 1: pair (grid-strided) + prep + focal + graph, fused ============
__global__ __launch_bounds__(256, 4) void main_kernel(const float* __restrict__ feat,
                                                      const float* __restrict__ preds,
                                                      const float* __restrict__ targets,
                                                      const float* __restrict__ gfeat,
                                                      float* __restrict__ vpart,
                                                      float* __restrict__ spart,
                                                      float* __restrict__ c_part,
                                                      float* __restrict__ f_part,
                                                      float* __restrict__ g_part) {
    __shared__ float fA[512], f1[512];
    __shared__ float sred[4][3];
    const int bx = blockIdx.x;
    const int tid = threadIdx.x;
    const int w = tid >> 6, lane = tid & 63;

    if (bx < G_PAIR) {
        // ---- 8 pair tiles per block; per-lane csum, ONE reduce at block end ----
        const int quad = lane >> 4, m15 = lane & 15;
        const int wm = w >> 1, wn = w & 1;
        float csum = 0.f;

        for (int t8 = 0; t8 < 8; ++t8) {
            const int u = bx * 8 + t8;
            const int vv = 2079 - u;
            int k = (int)((sqrtf(8.f * (float)vv + 1.f) - 1.f) * 0.5f);
            while ((k + 1) * (k + 2) / 2 <= vv) ++k;
            while (k * (k + 1) / 2 > vv) --k;
            const int bi = 63 - k;
            const int bj = 63 - (vv - k * (k + 1) / 2);
            const int ibase = bi * 128 + wm * 64, jbase = bj * 128 + wn * 64;

            // screen fragments: dims 0..31; lane(quad,m15) = row t*16+m15
            bf16x8 afs[4], bfs[4];
            float sA[4], sB[4];
            #pragma unroll
            for (int t = 0; t < 4; ++t) {
                const float* pa = feat + (ibase + t * 16 + m15) * DIM + 8 * quad;
                const float4 a0 = *reinterpret_cast<const float4*>(pa);
                const float4 a1 = *reinterpret_cast<const float4*>(pa + 4);
                afs[t] = pack8(a0, a1);
                float s = ssq8(a0, a1);
                s += __shfl_xor(s, 16); s += __shfl_xor(s, 32);
                sA[t] = s;
                const float* pb = feat + (jbase + t * 16 + m15) * DIM + 8 * quad;
                const float4 b0 = *reinterpret_cast<const float4*>(pb);
                const float4 b1 = *reinterpret_cast<const float4*>(pb + 4);
                bfs[t] = pack8(b0, b1);
                float sb = ssq8(b0, b1);
                sb += __shfl_xor(sb, 16); sb += __shfl_xor(sb, 32);
                sB[t] = sb;
            }
            f32x4 acc[4][4];
            #pragma unroll
            for (int a = 0; a < 4; ++a)
                #pragma unroll
                for (int b = 0; b < 4; ++b) acc[a][b] = (f32x4){0.f, 0.f, 0.f, 0.f};
            #pragma unroll
            for (int tm = 0; tm < 4; ++tm)
                #pragma unroll
                for (int tn = 0; tn < 4; ++tn)
                    acc[tm][tn] = __builtin_amdgcn_mfma_f32_16x16x32_bf16(
                        afs[tm], bfs[tn], acc[tm][tn], 0, 0, 0);

            float minv = 1e30f;
            #pragma unroll
            for (int tm = 0; tm < 4; ++tm) {
                #pragma unroll
                for (int e = 0; e < 4; ++e) {
                    const float sa = __shfl(sA[tm], quad * 4 + e);
                    #pragma unroll
                    for (int tn = 0; tn < 4; ++tn)
                        minv = fminf(minv, sa + sB[tn] - 2.f * acc[tm][tn][e]);
                }
            }

            if (__any(minv < 2.f)) {
                // exact f32 row norms: one i-row + one j-row per lane
                float qi = 0.f, qj = 0.f;
                {
                    const float4* ri = reinterpret_cast<const float4*>(feat + (ibase + lane) * DIM);
                    const float4* rj = reinterpret_cast<const float4*>(feat + (jbase + lane) * DIM);
                    #pragma unroll 8
                    for (int c2 = 0; c2 < 32; ++c2) {
                        const float4 x = ri[c2]; qi += x.x * x.x + x.y * x.y + x.z * x.z + x.w * x.w;
                        const float4 y = rj[c2]; qj += y.x * y.x + y.y * y.y + y.z * y.z + y.w * y.w;
                    }
                }
                f32x4 sqni[4], ti4[4];
                float sqnj[4], tj4[4];
                #pragma unroll
                for (int tm = 0; tm < 4; ++tm) {
                    #pragma unroll
                    for (int e = 0; e < 4; ++e) sqni[tm][e] = __shfl(qi, tm * 16 + quad * 4 + e);
                    ti4[tm] = *reinterpret_cast<const f32x4*>(targets + ibase + tm * 16 + quad * 4);
                }
                #pragma unroll
                for (int tn = 0; tn < 4; ++tn) {
                    sqnj[tn] = __shfl(qj, tn * 16 + m15);
                    tj4[tn] = targets[jbase + tn * 16 + m15];
                }
                // finish gram: dims 32..127
                for (int ks = 1; ks < 4; ++ks) {
                    bf16x8 af2[4], bf2[4];
                    #pragma unroll
                    for (int t = 0; t < 4; ++t) {
                        const float* pa = feat + (ibase + t * 16 + m15) * DIM + 8 * (quad + 4 * ks);
                        af2[t] = pack8(*reinterpret_cast<const float4*>(pa),
                                       *reinterpret_cast<const float4*>(pa + 4));
                        const float* pb = feat + (jbase + t * 16 + m15) * DIM + 8 * (quad + 4 * ks);
                        bf2[t] = pack8(*reinterpret_cast<const float4*>(pb),
                                       *reinterpret_cast<const float4*>(pb + 4));
                    }
                    #pragma unroll
                    for (int tm = 0; tm < 4; ++tm)
                        #pragma unroll
                        for (int tn = 0; tn < 4; ++tn)
                            acc[tm][tn] = __builtin_amdgcn_mfma_f32_16x16x32_bf16(
                                af2[tm], bf2[tn], acc[tm][tn], 0, 0, 0);
                }
                csum += (bi == bj)
                    ? scan_slow<true >(acc, sqni, ti4, sqnj, tj4, wm, wn, quad, m15)
                    : scan_slow<false>(acc, sqni, ti4, sqnj, tj4, wm, wn, quad, m15);
            }
        }
        #pragma unroll
        for (int off = 32; off > 0; off >>= 1) csum += __shfl_down(csum, off);
        if (lane == 0) c_part[bx * 4 + w] = csum;
    } else if (bx < G_PAIR + G_PREP) {
        // ---- prep: 4 column-sum chunks of 64 rows each ----
        const int pb = bx - G_PAIR;
        const float2* feat2 = reinterpret_cast<const float2*>(feat);
        for (int sub = 0; sub < 4; ++sub) {
            const int b = pb * 4 + sub;
            float2 accA = {0.f, 0.f}, acc1 = {0.f, 0.f};
            float ssqA = 0.f, ssq1 = 0.f, n1 = 0.f;
            int r = b * 64 + w * 16;
            #pragma unroll 4
            for (int i = 0; i < 16; ++i, ++r) {
                const float2 v = feat2[r * 64 + lane];
                const float tr = targets[r];              // wave-uniform
                accA.x += v.x; accA.y += v.y;
                acc1.x += tr * v.x; acc1.y += tr * v.y;
                const float s2 = v.x * v.x + v.y * v.y;
                ssqA += s2; ssq1 += tr * s2; n1 += tr;
            }
            fA[w * 128 + 2 * lane] = accA.x; fA[w * 128 + 2 * lane + 1] = accA.y;
            f1[w * 128 + 2 * lane] = acc1.x; f1[w * 128 + 2 * lane + 1] = acc1.y;
            #pragma unroll
            for (int off = 32; off > 0; off >>= 1) {
                ssqA += __shfl_down(ssqA, off);
                ssq1 += __shfl_down(ssq1, off);
            }
            if (lane == 0) { sred[w][0] = ssqA; sred[w][1] = ssq1; sred[w][2] = n1; }
            __syncthreads();
            if (tid < 128) {
                const int d = tid;
                const float c1 = f1[d] + f1[128 + d] + f1[256 + d] + f1[384 + d];
                const float ca = fA[d] + fA[128 + d] + fA[256 + d] + fA[384 + d];
                vpart[b * 256 + tid] = ca - c1;           // class 0
            } else {
                const int d = tid - 128;
                vpart[b * 256 + tid] = f1[d] + f1[128 + d] + f1[256 + d] + f1[384 + d];
            }
            if (tid == 0) {
                float4 s;
                s.x = sred[0][0] + sred[1][0] + sred[2][0] + sred[3][0];
                s.y = sred[0][1] + sred[1][1] + sred[2][1] + sred[3][1];
                s.z = sred[0][2] + sred[1][2] + sred[2][2] + sred[3][2];
                s.w = 0.f;
                *reinterpret_cast<float4*>(spart + b * 4) = s;
            }
            __syncthreads();   // smem reused next sub
        }
    } else if (bx < G_PAIR + G_PREP + G_FOCAL) {
        // ---- focal: 2048 elements per block ----
        const int b = bx - G_PAIR - G_PREP;
        float fv = 0.f;
        #pragma unroll
        for (int it = 0; it < 8; ++it) {
            const int i = b * 2048 + it * 256 + tid;
            const float p = preds[i], t = targets[i];
            const float bce = fmaxf(p, 0.f) - p * t + log1pf(expf(-fabsf(p)));
            const float pt = expf(-bce);
            const float om = 1.f - pt;
            fv += 0.25f * om * om * bce;
        }
        #pragma unroll
        for (int off = 32; off > 0; off >>= 1) fv += __shfl_down(fv, off);
        if (lane == 0) f_part[b * 4 + w] = fv;
    } else {
        // ---- graph: 128 rows per block; 4 independent shfl trees per iter ----
        const int b = bx - G_PAIR - G_PREP - G_FOCAL;
        float ga = 0.f;
        for (int it = 0; it < 8; ++it) {
            const int rbase = b * 128 + w * 32 + it * 4;
            float s[4];
            #pragma unroll
            for (int q = 0; q < 4; ++q) {
                const int r = rbase + q;
                if (r < N_PTS - 1) {
                    const float2 a = *reinterpret_cast<const float2*>(gfeat + r * DIM + lane * 2);
                    const float2 bb = *reinterpret_cast<const float2*>(gfeat + (r + 1) * DIM + lane * 2);
                    const float dx = bb.x - a.x, dy = bb.y - a.y;
                    s[q] = dx * dx + dy * dy;
                } else s[q] = 0.f;
            }
            #pragma unroll
            for (int off = 32; off > 0; off >>= 1) {
                s[0] += __shfl_down(s[0], off);
                s[1] += __shfl_down(s[1], off);
                s[2] += __shfl_down(s[2], off);
                s[3] += __shfl_down(s[3], off);
            }
            if (lane == 0) {
                #pragma unroll
                for (int q = 0; q < 4; ++q)
                    if (rbase + q < N_PTS - 1) ga += sqrtf(s[q]);
            }
        }
        if (lane == 0) g_part[b * 4 + w] = ga;
    }
}

// ================= launch 2: finalize (1 block) ================================
__global__ __launch_bounds__(256) void finalize_kernel(const float* __restrict__ c_part,
                                                       const float* __restrict__ f_part,
                                                       const float* __restrict__ g_part,
                                                       const float* __restrict__ vpart,
                                                       const float* __restrict__ spart,
                                                       float* __restrict__ out) {
    __shared__ double sC[4], sF[4], sG[4], sV[4], sST[4], sS1[4], sN1[4];
    const int tid = threadIdx.x;
    const int w = tid >> 6, lane = tid & 63;

    double c = 0.0;
    for (int i = tid; i < G_PAIR * 4; i += 256) c += (double)c_part[i];
    double f = (tid < G_FOCAL * 4) ? (double)f_part[tid] : 0.0;
    double g = (tid < G_GRAPH * 4) ? (double)g_part[tid] : 0.0;

    float V = 0.f;
    #pragma unroll 8
    for (int b2 = 0; b2 < 128; ++b2) V += vpart[b2 * 256 + tid];
    double vsq = (double)V * (double)V;   // tid<128: class0 dims; else class1

    double st = 0.0, s1 = 0.0, n1 = 0.0;
    if (tid < 128) {
        const float4 s = *reinterpret_cast<const float4*>(spart + tid * 4);
        st = s.x; s1 = s.y; n1 = s.z;
    }
    #pragma unroll
    for (int off = 32; off > 0; off >>= 1) {
        c += __shfl_down(c, off);
        f += __shfl_down(f, off);
        g += __shfl_down(g, off);
        vsq += __shfl_down(vsq, off);
        st += __shfl_down(st, off);
        s1 += __shfl_down(s1, off);
        n1 += __shfl_down(n1, off);
    }
    if (lane == 0) {
        sC[w] = c; sF[w] = f; sG[w] = g; sV[w] = vsq;
        sST[w] = st; sS1[w] = s1; sN1[w] = n1;
    }
    __syncthreads();
    if (tid == 0) {
        const double cs = sC[0] + sC[1] + sC[2] + sC[3];
        const double fs = sF[0] + sF[1] + sF[2] + sF[3];
        const double gs = sG[0] + sG[1] + sG[2] + sG[3];
        const double v0sq = sV[0] + sV[1];           // waves 0,1 = class0
        const double v1sq = sV[2] + sV[3];
        const double stot = sST[0] + sST[1] + sST[2] + sST[3];
        const double s1s  = sS1[0] + sS1[1] + sS1[2] + sS1[3];
        const double n1s  = sN1[0] + sN1[1] + sN1[2] + sN1[3];
        const double n0s = (double)N_PTS - n1s;
        const double s0s = stot - s1s;
        const double same = 2.0 * (n0s * s0s - v0sq) + 2.0 * (n1s * s1s - v1sq);
        out[0] = (float)((cs + same) / ((double)N_PTS * (double)N_PTS)
                         + fs / (double)N_PTS
                         + 0.1 * (gs / (double)(N_PTS - 1)));
    }
}

extern "C" void kernel_launch(void* const* d_in, const int* in_sizes, int n_in,
                              void* d_out, int out_size, void* d_ws, size_t ws_size,
                              hipStream_t stream) {
    const float* preds    = (const float*)d_in[0];
    const float* targets  = (const float*)d_in[1];
    const float* features = (const float*)d_in[2];
    const float* gfeat    = (const float*)d_in[3];
    char* ws = (char*)d_ws;
    float* vpart  = (float*)(ws + VPART_OFF);
    float* spart  = (float*)(ws + SPART_OFF);
    float* c_part = (float*)(ws + CPART_OFF);
    float* f_part = (float*)(ws + FPART_OFF);
    float* g_part = (float*)(ws + GPART_OFF);
    float* out = (float*)d_out;

    main_kernel<<<NMAIN, 256, 0, stream>>>(features, preds, targets, gfeat,
                                           vpart, spart, c_part, f_part, g_part);
    finalize_kernel<<<1, 256, 0, stream>>>(c_part, f_part, g_part, vpart, spart, out);
}

// Round 5
// 107.859 us; speedup vs baseline: 1.3873x; 1.3873x over previous
//
#include <hip/hip_runtime.h>
#include <hip/hip_bf16.h>

// HybridLoss: focal + contrastive + 0.1*graph_reg.  N=8192, D=128.
// v5: latency-chain fix.  v4 falsified "per-block overhead" (360 blocks was
// 2x SLOWER than 2368); v3/v4 are memory-latency-bound: scattered per-lane
// row-strided screen loads + ~34-shfl dependency chain per tile, too few
// waves to hide it.  v5 restores round-0 v1's fast screen (augmented-row
// MFMA emits the sq24 bound directly -- no shfls) but builds the panels
// per-block in LDS from dense 96B/row reads => no global staging pipeline,
// still 2 launches.  Slow path (diag tiles only) = v2's verified scattered
// f32 path with full ks=0..3 gram (screen acc holds sq24, not dot32).
// Cross-block dataflow: plain distinct-slot stores + kernel boundary.
//  - A-row = [-2f0..-2f23, sqn24, 1, 0x6], B-row = [f0..f23, 1, sqn24, 0x6]
//    => one K=32 MFMA per 16x16 tile gives sq24_ij in acc; wave-min >= 2
//    (bf16 slack) => tile has no margin-active pair (verified v1, absmax 0).
//  - same-label pairs: closed form 2*n_c*S_c - 2*||sum_c f||^2 in finalize.

#define N_PTS 8192
#define DIM 128

typedef __bf16 bf16x8 __attribute__((ext_vector_type(8)));
typedef float f32x4 __attribute__((ext_vector_type(4)));

// grid partition (main_kernel)
#define NPAIR 2080
#define NPREP 128
#define NFOCAL 32
#define NGRAPH 256
#define NMAIN (NPAIR + NPREP + NFOCAL + NGRAPH)

// workspace layout (bytes)
#define VPART_OFF 0                      // float[128][256] col sums (cls0 | cls1)
#define SPART_OFF 131072                 // float4[128] : {ssq_all, ssq_cls1, n1, 0}
#define CPART_OFF 133120                 // float[2080*4] pair per-wave partials
#define FPART_OFF 166400                 // float[32*4]   focal per-wave partials
#define GPART_OFF 166912                 // float[256*4]  graph per-wave partials

// LDS layout (pair branch): A panel 8KB | B panel 8KB | s24A 1KB | s24B 1KB
// unit(g,q,m) = ((g*4+q)*16 + m)*16 bytes; row r=g*16+m holds dims 8q..8q+7.
#define LDS_BYTES (8192 + 8192 + 1024 + 1024)
__device__ __forceinline__ int uoff(int g, int q, int m) {
    return ((g * 4 + q) * 16 + m) * 16;
}

__device__ __forceinline__ float ssq4(const float4 a) {
    return a.x * a.x + a.y * a.y + a.z * a.z + a.w * a.w;
}
__device__ __forceinline__ void store8(void* dst, float4 a, float4 b, float sc) {
    union { __bf16 h[8]; uint4 u; } p;
    p.h[0] = (__bf16)(sc * a.x); p.h[1] = (__bf16)(sc * a.y);
    p.h[2] = (__bf16)(sc * a.z); p.h[3] = (__bf16)(sc * a.w);
    p.h[4] = (__bf16)(sc * b.x); p.h[5] = (__bf16)(sc * b.y);
    p.h[6] = (__bf16)(sc * b.z); p.h[7] = (__bf16)(sc * b.w);
    *reinterpret_cast<uint4*>(dst) = p.u;
}
__device__ __forceinline__ void store4(void* dst, float4 a, float sc) {
    union { __bf16 h[4]; uint2 u; } p;
    p.h[0] = (__bf16)(sc * a.x); p.h[1] = (__bf16)(sc * a.y);
    p.h[2] = (__bf16)(sc * a.z); p.h[3] = (__bf16)(sc * a.w);
    *reinterpret_cast<uint2*>(dst) = p.u;
}
__device__ __forceinline__ bf16x8 pack8(const float4 a, const float4 b) {
    bf16x8 r;
    r[0] = (__bf16)a.x; r[1] = (__bf16)a.y; r[2] = (__bf16)a.z; r[3] = (__bf16)a.w;
    r[4] = (__bf16)b.x; r[5] = (__bf16)b.y; r[6] = (__bf16)b.z; r[7] = (__bf16)b.w;
    return r;
}

// ================= slow-path scan (unchanged, verified v1-v4) ==================
template<bool DIAG>
__device__ __forceinline__ float scan_slow(const f32x4 (&acc)[4][4],
                                           const f32x4 (&sqni)[4], const f32x4 (&ti4)[4],
                                           const float (&sqnj)[4], const float (&tj4)[4],
                                           int wm, int wn, int quad, int m15) {
    float lsum = 0.f;
    #pragma unroll
    for (int tm = 0; tm < 4; ++tm) {
        #pragma unroll
        for (int tn = 0; tn < 4; ++tn) {
            const int jl = wn * 64 + tn * 16 + m15;
            #pragma unroll
            for (int e = 0; e < 4; ++e) {
                const float sq = sqni[tm][e] + sqnj[tn] - 2.f * acc[tm][tn][e];
                bool excl = (ti4[tm][e] == tj4[tn]);
                if (DIAG) {
                    const int il = wm * 64 + tm * 16 + quad * 4 + e;
                    excl = excl || (jl <= il);
                }
                if (!excl && sq < 1.f) {
                    const float d = sqrtf(fmaxf(sq, 0.f));
                    const float m = 1.f - d;
                    lsum += 2.f * m * m;
                }
            }
        }
    }
    return lsum;
}

// ====== launch 1: pair (LDS-self-staged screen) + prep + focal + graph =========
__global__ __launch_bounds__(256, 4) void main_kernel(const float* __restrict__ feat,
                                                      const float* __restrict__ preds,
                                                      const float* __restrict__ targets,
                                                      const float* __restrict__ gfeat,
                                                      float* __restrict__ vpart,
                                                      float* __restrict__ spart,
                                                      float* __restrict__ c_part,
                                                      float* __restrict__ f_part,
                                                      float* __restrict__ g_part) {
    __shared__ __align__(16) char smem[LDS_BYTES];
    const int bx = blockIdx.x;
    const int tid = threadIdx.x;
    const int w = tid >> 6, lane = tid & 63;

    if (bx < NPAIR) {
        // ---- pair block: one 128x128 tile (bi, bj), bi <= bj ----
        const int u = bx;
        const int vv = 2079 - u;
        int k = (int)((sqrtf(8.f * (float)vv + 1.f) - 1.f) * 0.5f);
        while ((k + 1) * (k + 2) / 2 <= vv) ++k;
        while (k * (k + 1) / 2 > vv) --k;
        const int bi = 63 - k;
        const int bj = 63 - (vv - k * (k + 1) / 2);

        const int quad = lane >> 4, m15 = lane & 15;
        const int wm = w >> 1, wn = w & 1;

        char* Ap = smem;
        char* Bp = smem + 8192;
        float* s24A = reinterpret_cast<float*>(smem + 16384);
        float* s24B = reinterpret_cast<float*>(smem + 17408);

        // ---- stage augmented screen panels into LDS (dense 96B/row reads) ----
        {
            const int r = tid >> 1, h = tid & 1;     // row 0..127, half 0/1
            const int g = r >> 4, m = r & 15;
            const float4* f4 = reinterpret_cast<const float4*>(feat);
            const int ab = (bi * 128 + r) * 32 + h * 3;
            const int bb = (bj * 128 + r) * 32 + h * 3;
            const float4 a0 = f4[ab], a1 = f4[ab + 1], a2 = f4[ab + 2];
            const float4 b0 = f4[bb], b1 = f4[bb + 1], b2 = f4[bb + 2];
            s24A[r * 2 + h] = ssq4(a0) + ssq4(a1) + ssq4(a2);
            s24B[r * 2 + h] = ssq4(b0) + ssq4(b1) + ssq4(b2);
            if (h == 0) {                            // dims 0..11
                store8(Ap + uoff(g, 0, m), a0, a1, -2.f);
                store4(Ap + uoff(g, 1, m), a2, -2.f);
                store8(Bp + uoff(g, 0, m), b0, b1, 1.f);
                store4(Bp + uoff(g, 1, m), b2, 1.f);
            } else {                                 // dims 12..23
                store4(Ap + uoff(g, 1, m) + 8, a0, -2.f);
                store8(Ap + uoff(g, 2, m), a1, a2, -2.f);
                store4(Bp + uoff(g, 1, m) + 8, b0, 1.f);
                store8(Bp + uoff(g, 2, m), b1, b2, 1.f);
            }
            __syncthreads();
            if (tid < 128) {                         // quad3: [sqn,1,0..] / [1,sqn,0..]
                const int rr = tid, gg = rr >> 4, mm = rr & 15;
                const float sqa = s24A[rr * 2] + s24A[rr * 2 + 1];
                const float sqb = s24B[rr * 2] + s24B[rr * 2 + 1];
                union { __bf16 x[8]; uint4 u; } ua, ub;
                #pragma unroll
                for (int i = 0; i < 8; ++i) { ua.x[i] = (__bf16)0.f; ub.x[i] = (__bf16)0.f; }
                ua.x[0] = (__bf16)sqa; ua.x[1] = (__bf16)1.f;
                ub.x[0] = (__bf16)1.f; ub.x[1] = (__bf16)sqb;
                *reinterpret_cast<uint4*>(Ap + uoff(gg, 3, mm)) = ua.u;
                *reinterpret_cast<uint4*>(Bp + uoff(gg, 3, mm)) = ub.u;
            }
            __syncthreads();
        }

        // ---- screen: conflict-free ds_read_b128 fragments + 16 MFMAs ----
        bf16x8 afs[4], bfs[4];
        #pragma unroll
        for (int t = 0; t < 4; ++t) {
            afs[t] = *reinterpret_cast<const bf16x8*>(Ap + uoff(wm * 4 + t, quad, m15));
            bfs[t] = *reinterpret_cast<const bf16x8*>(Bp + uoff(wn * 4 + t, quad, m15));
        }
        f32x4 acc[4][4];
        #pragma unroll
        for (int a = 0; a < 4; ++a)
            #pragma unroll
            for (int b = 0; b < 4; ++b) acc[a][b] = (f32x4){0.f, 0.f, 0.f, 0.f};
        #pragma unroll
        for (int tm = 0; tm < 4; ++tm)
            #pragma unroll
            for (int tn = 0; tn < 4; ++tn)
                acc[tm][tn] = __builtin_amdgcn_mfma_f32_16x16x32_bf16(
                    afs[tm], bfs[tn], acc[tm][tn], 0, 0, 0);

        // acc IS sq24 (augmented rows) -- pure-VALU min, no shuffles
        float minv = 1e30f;
        #pragma unroll
        for (int tm = 0; tm < 4; ++tm)
            #pragma unroll
            for (int tn = 0; tn < 4; ++tn)
                #pragma unroll
                for (int e = 0; e < 4; ++e)
                    minv = fminf(minv, acc[tm][tn][e]);

        float lsum = 0.f;
        if (__any(minv < 2.f)) {
            // ---- exact slow path (diag + rare near-pairs), from f32 feat ----
            const int ibase = bi * 128 + wm * 64, jbase = bj * 128 + wn * 64;
            float qi = 0.f, qj = 0.f;
            {
                const float4* ri = reinterpret_cast<const float4*>(feat + (ibase + lane) * DIM);
                const float4* rj = reinterpret_cast<const float4*>(feat + (jbase + lane) * DIM);
                #pragma unroll 8
                for (int c2 = 0; c2 < 32; ++c2) {
                    const float4 x = ri[c2]; qi += x.x * x.x + x.y * x.y + x.z * x.z + x.w * x.w;
                    const float4 y = rj[c2]; qj += y.x * y.x + y.y * y.y + y.z * y.z + y.w * y.w;
                }
            }
            f32x4 sqni[4], ti4[4];
            float sqnj[4], tj4[4];
            #pragma unroll
            for (int tm = 0; tm < 4; ++tm) {
                #pragma unroll
                for (int e = 0; e < 4; ++e) sqni[tm][e] = __shfl(qi, tm * 16 + quad * 4 + e);
                ti4[tm] = *reinterpret_cast<const f32x4*>(targets + ibase + tm * 16 + quad * 4);
            }
            #pragma unroll
            for (int tn = 0; tn < 4; ++tn) {
                sqnj[tn] = __shfl(qj, tn * 16 + m15);
                tj4[tn] = targets[jbase + tn * 16 + m15];
            }
            // full K=128 gram from scratch (screen acc held sq24, not dot)
            #pragma unroll
            for (int a = 0; a < 4; ++a)
                #pragma unroll
                for (int b = 0; b < 4; ++b) acc[a][b] = (f32x4){0.f, 0.f, 0.f, 0.f};
            for (int ks = 0; ks < 4; ++ks) {
                bf16x8 af2[4], bf2[4];
                #pragma unroll
                for (int t = 0; t < 4; ++t) {
                    const float* pa = feat + (ibase + t * 16 + m15) * DIM + 8 * (quad + 4 * ks);
                    af2[t] = pack8(*reinterpret_cast<const float4*>(pa),
                                   *reinterpret_cast<const float4*>(pa + 4));
                    const float* pb = feat + (jbase + t * 16 + m15) * DIM + 8 * (quad + 4 * ks);
                    bf2[t] = pack8(*reinterpret_cast<const float4*>(pb),
                                   *reinterpret_cast<const float4*>(pb + 4));
                }
                #pragma unroll
                for (int tm = 0; tm < 4; ++tm)
                    #pragma unroll
                    for (int tn = 0; tn < 4; ++tn)
                        acc[tm][tn] = __builtin_amdgcn_mfma_f32_16x16x32_bf16(
                            af2[tm], bf2[tn], acc[tm][tn], 0, 0, 0);
            }
            lsum = (bi == bj)
                ? scan_slow<true >(acc, sqni, ti4, sqnj, tj4, wm, wn, quad, m15)
                : scan_slow<false>(acc, sqni, ti4, sqnj, tj4, wm, wn, quad, m15);
            #pragma unroll
            for (int off = 32; off > 0; off >>= 1) lsum += __shfl_down(lsum, off);
        }
        if (lane == 0) c_part[u * 4 + w] = lsum;     // distinct slot per wave
    } else if (bx < NPAIR + NPREP) {
        // ---- prep: 64-row column-sum chunk (verified v3) ----
        const int b = bx - NPAIR;
        float* fA = reinterpret_cast<float*>(smem);          // [4][128]
        float* f1 = reinterpret_cast<float*>(smem + 2048);   // [4][128]
        float (*sred)[3] = reinterpret_cast<float(*)[3]>(smem + 4096);
        const float2* feat2 = reinterpret_cast<const float2*>(feat);
        float2 accA = {0.f, 0.f}, acc1 = {0.f, 0.f};
        float ssqA = 0.f, ssq1 = 0.f, n1 = 0.f;
        int r = b * 64 + w * 16;
        #pragma unroll 4
        for (int i = 0; i < 16; ++i, ++r) {
            const float2 v = feat2[r * 64 + lane];
            const float tr = targets[r];              // wave-uniform
            accA.x += v.x; accA.y += v.y;
            acc1.x += tr * v.x; acc1.y += tr * v.y;
            const float s2 = v.x * v.x + v.y * v.y;
            ssqA += s2; ssq1 += tr * s2; n1 += tr;
        }
        fA[w * 128 + 2 * lane] = accA.x; fA[w * 128 + 2 * lane + 1] = accA.y;
        f1[w * 128 + 2 * lane] = acc1.x; f1[w * 128 + 2 * lane + 1] = acc1.y;
        #pragma unroll
        for (int off = 32; off > 0; off >>= 1) {
            ssqA += __shfl_down(ssqA, off);
            ssq1 += __shfl_down(ssq1, off);
        }
        if (lane == 0) { sred[w][0] = ssqA; sred[w][1] = ssq1; sred[w][2] = n1; }
        __syncthreads();
        if (tid < 128) {
            const int d = tid;
            const float c1 = f1[d] + f1[128 + d] + f1[256 + d] + f1[384 + d];
            const float ca = fA[d] + fA[128 + d] + fA[256 + d] + fA[384 + d];
            vpart[b * 256 + tid] = ca - c1;           // class 0
        } else {
            const int d = tid - 128;
            vpart[b * 256 + tid] = f1[d] + f1[128 + d] + f1[256 + d] + f1[384 + d];
        }
        if (tid == 0) {
            float4 s;
            s.x = sred[0][0] + sred[1][0] + sred[2][0] + sred[3][0];
            s.y = sred[0][1] + sred[1][1] + sred[2][1] + sred[3][1];
            s.z = sred[0][2] + sred[1][2] + sred[2][2] + sred[3][2];
            s.w = 0.f;
            *reinterpret_cast<float4*>(spart + b * 4) = s;
        }
    } else if (bx < NPAIR + NPREP + NFOCAL) {
        // ---- focal (verified v3) ----
        const int b = bx - NPAIR - NPREP;
        const int i = b * 256 + tid;
        const float p = preds[i], t = targets[i];
        const float bce = fmaxf(p, 0.f) - p * t + log1pf(expf(-fabsf(p)));
        const float pt = expf(-bce);
        const float om = 1.f - pt;
        float fv = 0.25f * om * om * bce;
        #pragma unroll
        for (int off = 32; off > 0; off >>= 1) fv += __shfl_down(fv, off);
        if (lane == 0) f_part[b * 4 + w] = fv;
    } else {
        // ---- graph regularizer (verified v3) ----
        const int b = bx - NPAIR - NPREP - NFOCAL;
        float ga = 0.f;
        #pragma unroll
        for (int it = 0; it < 8; ++it) {
            const int r = b * 4 + w + it * 1024;
            if (r < N_PTS - 1) {
                const float2 a = *reinterpret_cast<const float2*>(gfeat + r * DIM + lane * 2);
                const float2 bb = *reinterpret_cast<const float2*>(gfeat + (r + 1) * DIM + lane * 2);
                const float dx = bb.x - a.x, dy = bb.y - a.y;
                float s = dx * dx + dy * dy;
                #pragma unroll
                for (int off = 32; off > 0; off >>= 1) s += __shfl_down(s, off);
                if (lane == 0) ga += sqrtf(s);
            }
        }
        if (lane == 0) g_part[b * 4 + w] = ga;
    }
}

// ================= launch 2: finalize (1 block, verified v3) ===================
__global__ __launch_bounds__(256) void finalize_kernel(const float* __restrict__ c_part,
                                                       const float* __restrict__ f_part,
                                                       const float* __restrict__ g_part,
                                                       const float* __restrict__ vpart,
                                                       const float* __restrict__ spart,
                                                       float* __restrict__ out) {
    __shared__ double sC[4], sF[4], sG[4], sV[4], sST[4], sS1[4], sN1[4];
    const int tid = threadIdx.x;
    const int w = tid >> 6, lane = tid & 63;

    double c = 0.0;
    for (int i = tid; i < NPAIR * 4; i += 256) c += (double)c_part[i];
    double f = (tid < NFOCAL * 4) ? (double)f_part[tid] : 0.0;
    double g = 0.0;
    for (int i = tid; i < NGRAPH * 4; i += 256) g += (double)g_part[i];

    float V = 0.f;
    #pragma unroll 8
    for (int b2 = 0; b2 < 128; ++b2) V += vpart[b2 * 256 + tid];
    double vsq = (double)V * (double)V;   // tid<128: class0 dims; else class1

    double st = 0.0, s1 = 0.0, n1 = 0.0;
    if (tid < 128) {
        const float4 s = *reinterpret_cast<const float4*>(spart + tid * 4);
        st = s.x; s1 = s.y; n1 = s.z;
    }
    #pragma unroll
    for (int off = 32; off > 0; off >>= 1) {
        c += __shfl_down(c, off);
        f += __shfl_down(f, off);
        g += __shfl_down(g, off);
        vsq += __shfl_down(vsq, off);
        st += __shfl_down(st, off);
        s1 += __shfl_down(s1, off);
        n1 += __shfl_down(n1, off);
    }
    if (lane == 0) {
        sC[w] = c; sF[w] = f; sG[w] = g; sV[w] = vsq;
        sST[w] = st; sS1[w] = s1; sN1[w] = n1;
    }
    __syncthreads();
    if (tid == 0) {
        const double cs = sC[0] + sC[1] + sC[2] + sC[3];
        const double fs = sF[0] + sF[1] + sF[2] + sF[3];
        const double gs = sG[0] + sG[1] + sG[2] + sG[3];
        const double v0sq = sV[0] + sV[1];           // waves 0,1 = class0
        const double v1sq = sV[2] + sV[3];
        const double stot = sST[0] + sST[1] + sST[2] + sST[3];
        const double s1s  = sS1[0] + sS1[1] + sS1[2] + sS1[3];
        const double n1s  = sN1[0] + sN1[1] + sN1[2] + sN1[3];
        const double n0s = (double)N_PTS - n1s;
        const double s0s = stot - s1s;
        const double same = 2.0 * (n0s * s0s - v0sq) + 2.0 * (n1s * s1s - v1sq);
        out[0] = (float)((cs + same) / ((double)N_PTS * (double)N_PTS)
                         + fs / (double)N_PTS
                         + 0.1 * (gs / (double)(N_PTS - 1)));
    }
}

extern "C" void kernel_launch(void* const* d_in, const int* in_sizes, int n_in,
                              void* d_out, int out_size, void* d_ws, size_t ws_size,
                              hipStream_t stream) {
    const float* preds    = (const float*)d_in[0];
    const float* targets  = (const float*)d_in[1];
    const float* features = (const float*)d_in[2];
    const float* gfeat    = (const float*)d_in[3];
    char* ws = (char*)d_ws;
    float* vpart  = (float*)(ws + VPART_OFF);
    float* spart  = (float*)(ws + SPART_OFF);
    float* c_part = (float*)(ws + CPART_OFF);
    float* f_part = (float*)(ws + FPART_OFF);
    float* g_part = (float*)(ws + GPART_OFF);
    float* out = (float*)d_out;

    main_kernel<<<NMAIN, 256, 0, stream>>>(features, preds, targets, gfeat,
                                           vpart, spart, c_part, f_part, g_part);
    finalize_kernel<<<1, 256, 0, stream>>>(c_part, f_part, g_part, vpart, spart, out);
}

// Round 6
// 107.636 us; speedup vs baseline: 1.3901x; 1.0021x over previous
//
#include <hip/hip_runtime.h>
#include <hip/hip_bf16.h>

// HybridLoss: focal + contrastive + 0.1*graph_reg.  N=8192, D=128.
// v6: workgroup-count reduction.  Cross-round law: dur ~= 15-19ns x #WGs,
// nearly independent of per-block work (v2 25ns, v3 18ns, v5 15ns per WG;
// v4's 360-WG regression was SERIAL per-wave tile chains, not the law's
// refutation).  v6 keeps per-tile work concurrent but packs 4 tiles into one
// 1024-thread block: 256x256 super-tiles, one 128x128 tile per wave-quad,
// shared LDS staging (staging volume also halves).  2496 -> 632 WGs.
//  - screen: v1/v5-verified augmented-row MFMA (A=[-2f0..23,sq24,1,0..],
//    B=[f0..23,1,sq24,0..]; one K=32 MFMA emits sq24; wave-min >= 2 => skip).
//  - slow path (diag tiles + never-in-practice near tiles): v5 verbatim.
//  - same-label pairs: closed form 2*n_c*S_c - 2*||sum_c f||^2 in finalize.
//  - cross-block dataflow: plain distinct-slot stores + kernel boundary
//    (no atomics: v2's one-address rendezvous; no fences: round-3 L2 thrash).

#define N_PTS 8192
#define DIM 128

typedef __bf16 bf16x8 __attribute__((ext_vector_type(8)));
typedef float f32x4 __attribute__((ext_vector_type(4)));

// grid partition (main_kernel, 1024-thread blocks)
#define NPAIRB 528           // 32*33/2 super-tiles of 256x256 (4 quads x 128x128)
#define NPREPB 32            // x4 quad-chunks = 128 column-sum chunks
#define NFOCALB 8            // x4 quad-chunks = 32 focal chunks
#define NGRAPHB 64           // x4 quad-chunks = 256 graph chunks
#define NMAIN (NPAIRB + NPREPB + NFOCALB + NGRAPHB)

// workspace layout (bytes)
#define VPART_OFF 0                      // float[128][256] col sums (cls0 | cls1)
#define SPART_OFF 131072                 // float4[128] : {ssq_all, ssq_cls1, n1, 0}
#define CPART_OFF 133120                 // float[528*16] pair per-wave partials
#define FPART_OFF 166912                 // float[32*4]   focal per-wave partials
#define GPART_OFF 167424                 // float[256*4]  graph per-wave partials

// LDS (pair): A panel 16K | B panel 16K | s24A 2K | s24B 2K = 36K
// unit(g,qd,m) = ((g*4+qd)*16+m)*16 bytes; panel row r=g*16+m, dims 8qd..8qd+7.
#define LDS_BYTES 36864
__device__ __forceinline__ int uoff(int g, int qd, int m) {
    return ((g * 4 + qd) * 16 + m) * 16;
}

__device__ __forceinline__ float ssq4(const float4 a) {
    return a.x * a.x + a.y * a.y + a.z * a.z + a.w * a.w;
}
__device__ __forceinline__ void store8(void* dst, float4 a, float4 b, float sc) {
    union { __bf16 h[8]; uint4 u; } p;
    p.h[0] = (__bf16)(sc * a.x); p.h[1] = (__bf16)(sc * a.y);
    p.h[2] = (__bf16)(sc * a.z); p.h[3] = (__bf16)(sc * a.w);
    p.h[4] = (__bf16)(sc * b.x); p.h[5] = (__bf16)(sc * b.y);
    p.h[6] = (__bf16)(sc * b.z); p.h[7] = (__bf16)(sc * b.w);
    *reinterpret_cast<uint4*>(dst) = p.u;
}
__device__ __forceinline__ void store4(void* dst, float4 a, float sc) {
    union { __bf16 h[4]; uint2 u; } p;
    p.h[0] = (__bf16)(sc * a.x); p.h[1] = (__bf16)(sc * a.y);
    p.h[2] = (__bf16)(sc * a.z); p.h[3] = (__bf16)(sc * a.w);
    *reinterpret_cast<uint2*>(dst) = p.u;
}
__device__ __forceinline__ bf16x8 pack8(const float4 a, const float4 b) {
    bf16x8 r;
    r[0] = (__bf16)a.x; r[1] = (__bf16)a.y; r[2] = (__bf16)a.z; r[3] = (__bf16)a.w;
    r[4] = (__bf16)b.x; r[5] = (__bf16)b.y; r[6] = (__bf16)b.z; r[7] = (__bf16)b.w;
    return r;
}

// ================= slow-path scan (unchanged, verified v1-v5) ==================
template<bool DIAG>
__device__ __forceinline__ float scan_slow(const f32x4 (&acc)[4][4],
                                           const f32x4 (&sqni)[4], const f32x4 (&ti4)[4],
                                           const float (&sqnj)[4], const float (&tj4)[4],
                                           int wm, int wn, int qd, int m15) {
    float lsum = 0.f;
    #pragma unroll
    for (int tm = 0; tm < 4; ++tm) {
        #pragma unroll
        for (int tn = 0; tn < 4; ++tn) {
            const int jl = wn * 64 + tn * 16 + m15;
            #pragma unroll
            for (int e = 0; e < 4; ++e) {
                const float sq = sqni[tm][e] + sqnj[tn] - 2.f * acc[tm][tn][e];
                bool excl = (ti4[tm][e] == tj4[tn]);
                if (DIAG) {
                    const int il = wm * 64 + tm * 16 + qd * 4 + e;
                    excl = excl || (jl <= il);
                }
                if (!excl && sq < 1.f) {
                    const float d = sqrtf(fmaxf(sq, 0.f));
                    const float m = 1.f - d;
                    lsum += 2.f * m * m;
                }
            }
        }
    }
    return lsum;
}

// ====== launch 1: pair super-tiles + prep + focal + graph (1024 threads) =======
__global__ __launch_bounds__(1024, 4) void main_kernel(const float* __restrict__ feat,
                                                       const float* __restrict__ preds,
                                                       const float* __restrict__ targets,
                                                       const float* __restrict__ gfeat,
                                                       float* __restrict__ vpart,
                                                       float* __restrict__ spart,
                                                       float* __restrict__ c_part,
                                                       float* __restrict__ f_part,
                                                       float* __restrict__ g_part) {
    __shared__ __align__(16) char smem[LDS_BYTES];
    const int bx = blockIdx.x;
    const int tid = threadIdx.x;
    const int w = tid >> 6, lane = tid & 63;

    if (bx < NPAIRB) {
        // ---- 256x256 super-tile (sbi, sbj), sbi <= sbj; quad q -> 128-tile ----
        const int u = bx;
        const int vv = 527 - u;
        int k = (int)((sqrtf(8.f * (float)vv + 1.f) - 1.f) * 0.5f);
        while ((k + 1) * (k + 2) / 2 <= vv) ++k;
        while (k * (k + 1) / 2 > vv) --k;
        const int sbi = 31 - k;
        const int sbj = 31 - (vv - k * (k + 1) / 2);

        char* Ap = smem;
        char* Bp = smem + 16384;
        float* s24A = reinterpret_cast<float*>(smem + 32768);  // [512]
        float* s24B = reinterpret_cast<float*>(smem + 34816);  // [512]

        // ---- stage both 256-row panels once (shared by all 4 quads) ----
        {
            const int r = tid >> 1, h = tid & 1;   // r 0..511, half 0/1
            const bool isA = r < 256;
            const int rr = isA ? r : r - 256;
            const int grow = (isA ? sbi : sbj) * 256 + rr;
            const float4* f4 = reinterpret_cast<const float4*>(feat);
            const int o = grow * 32 + h * 3;
            const float4 a0 = f4[o], a1 = f4[o + 1], a2 = f4[o + 2];
            const int g = rr >> 4, m = rr & 15;
            char* P = isA ? Ap : Bp;
            const float sc = isA ? -2.f : 1.f;
            (isA ? s24A : s24B)[rr * 2 + h] = ssq4(a0) + ssq4(a1) + ssq4(a2);
            if (h == 0) {                          // dims 0..11
                store8(P + uoff(g, 0, m), a0, a1, sc);
                store4(P + uoff(g, 1, m), a2, sc);
            } else {                               // dims 12..23
                store4(P + uoff(g, 1, m) + 8, a0, sc);
                store8(P + uoff(g, 2, m), a1, a2, sc);
            }
            __syncthreads();
            if (tid < 256) {                       // qd3 augment rows
                const int gg = tid >> 4, mm = tid & 15;
                const float sqa = s24A[tid * 2] + s24A[tid * 2 + 1];
                const float sqb = s24B[tid * 2] + s24B[tid * 2 + 1];
                union { __bf16 x[8]; uint4 uu; } ua, ub;
                #pragma unroll
                for (int i2 = 0; i2 < 8; ++i2) { ua.x[i2] = (__bf16)0.f; ub.x[i2] = (__bf16)0.f; }
                ua.x[0] = (__bf16)sqa; ua.x[1] = (__bf16)1.f;
                ub.x[0] = (__bf16)1.f; ub.x[1] = (__bf16)sqb;
                *reinterpret_cast<uint4*>(Ap + uoff(gg, 3, mm)) = ua.uu;
                *reinterpret_cast<uint4*>(Bp + uoff(gg, 3, mm)) = ub.uu;
            }
            __syncthreads();
        }

        const int qd = lane >> 4, m15 = lane & 15;
        const int q = w >> 2, wq = w & 3;          // quad 0..3, wave-in-quad 0..3
        const int qm = q >> 1, qn = q & 1;
        const int BI = sbi * 2 + qm, BJ = sbj * 2 + qn;
        const int wm = wq >> 1, wn = wq & 1;
        const bool active = (BI <= BJ);            // lower quad only in diag supertile

        // ---- screen: conflict-free b128 fragment reads + 16 MFMAs per wave ----
        bf16x8 afs[4], bfs[4];
        #pragma unroll
        for (int t = 0; t < 4; ++t) {
            afs[t] = *reinterpret_cast<const bf16x8*>(Ap + uoff(qm * 8 + wm * 4 + t, qd, m15));
            bfs[t] = *reinterpret_cast<const bf16x8*>(Bp + uoff(qn * 8 + wn * 4 + t, qd, m15));
        }
        f32x4 acc[4][4];
        #pragma unroll
        for (int a = 0; a < 4; ++a)
            #pragma unroll
            for (int b = 0; b < 4; ++b) acc[a][b] = (f32x4){0.f, 0.f, 0.f, 0.f};
        #pragma unroll
        for (int tm = 0; tm < 4; ++tm)
            #pragma unroll
            for (int tn = 0; tn < 4; ++tn)
                acc[tm][tn] = __builtin_amdgcn_mfma_f32_16x16x32_bf16(
                    afs[tm], bfs[tn], acc[tm][tn], 0, 0, 0);

        // acc IS sq24 (augmented rows): pure-VALU min
        float minv = 1e30f;
        #pragma unroll
        for (int tm = 0; tm < 4; ++tm)
            #pragma unroll
            for (int tn = 0; tn < 4; ++tn)
                #pragma unroll
                for (int e = 0; e < 4; ++e)
                    minv = fminf(minv, acc[tm][tn][e]);
        if (!active) minv = 1e30f;

        float lsum = 0.f;
        if (__any(minv < 2.f)) {
            // ---- exact slow path (v5 verbatim; diag tiles in practice) ----
            const int ibase = BI * 128 + wm * 64, jbase = BJ * 128 + wn * 64;
            float qi = 0.f, qj = 0.f;
            {
                const float4* ri = reinterpret_cast<const float4*>(feat + (ibase + lane) * DIM);
                const float4* rj = reinterpret_cast<const float4*>(feat + (jbase + lane) * DIM);
                #pragma unroll 8
                for (int c2 = 0; c2 < 32; ++c2) {
                    const float4 x = ri[c2]; qi += x.x * x.x + x.y * x.y + x.z * x.z + x.w * x.w;
                    const float4 y = rj[c2]; qj += y.x * y.x + y.y * y.y + y.z * y.z + y.w * y.w;
                }
            }
            f32x4 sqni[4], ti4[4];
            float sqnj[4], tj4[4];
            #pragma unroll
            for (int tm = 0; tm < 4; ++tm) {
                #pragma unroll
                for (int e = 0; e < 4; ++e) sqni[tm][e] = __shfl(qi, tm * 16 + qd * 4 + e);
                ti4[tm] = *reinterpret_cast<const f32x4*>(targets + ibase + tm * 16 + qd * 4);
            }
            #pragma unroll
            for (int tn = 0; tn < 4; ++tn) {
                sqnj[tn] = __shfl(qj, tn * 16 + m15);
                tj4[tn] = targets[jbase + tn * 16 + m15];
            }
            #pragma unroll
            for (int a = 0; a < 4; ++a)
                #pragma unroll
                for (int b = 0; b < 4; ++b) acc[a][b] = (f32x4){0.f, 0.f, 0.f, 0.f};
            for (int ks = 0; ks < 4; ++ks) {
                bf16x8 af2[4], bf2[4];
                #pragma unroll
                for (int t = 0; t < 4; ++t) {
                    const float* pa = feat + (ibase + t * 16 + m15) * DIM + 8 * (qd + 4 * ks);
                    af2[t] = pack8(*reinterpret_cast<const float4*>(pa),
                                   *reinterpret_cast<const float4*>(pa + 4));
                    const float* pb = feat + (jbase + t * 16 + m15) * DIM + 8 * (qd + 4 * ks);
                    bf2[t] = pack8(*reinterpret_cast<const float4*>(pb),
                                   *reinterpret_cast<const float4*>(pb + 4));
                }
                #pragma unroll
                for (int tm = 0; tm < 4; ++tm)
                    #pragma unroll
                    for (int tn = 0; tn < 4; ++tn)
                        acc[tm][tn] = __builtin_amdgcn_mfma_f32_16x16x32_bf16(
                            af2[tm], bf2[tn], acc[tm][tn], 0, 0, 0);
            }
            lsum = (BI == BJ)
                ? scan_slow<true >(acc, sqni, ti4, sqnj, tj4, wm, wn, qd, m15)
                : scan_slow<false>(acc, sqni, ti4, sqnj, tj4, wm, wn, qd, m15);
            #pragma unroll
            for (int off = 32; off > 0; off >>= 1) lsum += __shfl_down(lsum, off);
        }
        if (lane == 0) c_part[u * 16 + w] = lsum;   // distinct slot per wave
    } else if (bx < NPAIRB + NPREPB) {
        // ---- prep: 4 quad-parallel 64-row column-sum chunks (v3-verified) ----
        const int cq = tid >> 8, t256 = tid & 255;
        const int w4 = (tid >> 6) & 3;
        const int chunk = (bx - NPAIRB) * 4 + cq;
        float* fA = reinterpret_cast<float*>(smem) + cq * 1024;    // [4][128]
        float* f1 = fA + 512;                                       // [4][128]
        float* sred = reinterpret_cast<float*>(smem + 16384);       // [4][4][3]
        const float2* feat2 = reinterpret_cast<const float2*>(feat);
        float2 accA = {0.f, 0.f}, acc1 = {0.f, 0.f};
        float ssqA = 0.f, ssq1 = 0.f, n1 = 0.f;
        int r = chunk * 64 + w4 * 16;
        #pragma unroll 4
        for (int i = 0; i < 16; ++i, ++r) {
            const float2 v = feat2[r * 64 + lane];
            const float tr = targets[r];              // wave-uniform
            accA.x += v.x; accA.y += v.y;
            acc1.x += tr * v.x; acc1.y += tr * v.y;
            const float s2 = v.x * v.x + v.y * v.y;
            ssqA += s2; ssq1 += tr * s2; n1 += tr;
        }
        fA[w4 * 128 + 2 * lane] = accA.x; fA[w4 * 128 + 2 * lane + 1] = accA.y;
        f1[w4 * 128 + 2 * lane] = acc1.x; f1[w4 * 128 + 2 * lane + 1] = acc1.y;
        #pragma unroll
        for (int off = 32; off > 0; off >>= 1) {
            ssqA += __shfl_down(ssqA, off);
            ssq1 += __shfl_down(ssq1, off);
        }
        if (lane == 0) {
            sred[(cq * 4 + w4) * 3 + 0] = ssqA;
            sred[(cq * 4 + w4) * 3 + 1] = ssq1;
            sred[(cq * 4 + w4) * 3 + 2] = n1;
        }
        __syncthreads();
        if (t256 < 128) {
            const int d = t256;
            const float c1 = f1[d] + f1[128 + d] + f1[256 + d] + f1[384 + d];
            const float ca = fA[d] + fA[128 + d] + fA[256 + d] + fA[384 + d];
            vpart[chunk * 256 + t256] = ca - c1;      // class 0
        } else {
            const int d = t256 - 128;
            vpart[chunk * 256 + t256] = f1[d] + f1[128 + d] + f1[256 + d] + f1[384 + d];
        }
        if (t256 == 0) {
            float4 s;
            s.x = sred[cq * 12 + 0] + sred[cq * 12 + 3] + sred[cq * 12 + 6] + sred[cq * 12 + 9];
            s.y = sred[cq * 12 + 1] + sred[cq * 12 + 4] + sred[cq * 12 + 7] + sred[cq * 12 + 10];
            s.z = sred[cq * 12 + 2] + sred[cq * 12 + 5] + sred[cq * 12 + 8] + sred[cq * 12 + 11];
            s.w = 0.f;
            *reinterpret_cast<float4*>(spart + chunk * 4) = s;
        }
    } else if (bx < NPAIRB + NPREPB + NFOCALB) {
        // ---- focal: 4 quad-parallel 256-elem chunks (v3-verified) ----
        const int cq = tid >> 8, t256 = tid & 255;
        const int w4 = (tid >> 6) & 3;
        const int chunk = (bx - NPAIRB - NPREPB) * 4 + cq;
        const int i = chunk * 256 + t256;
        const float p = preds[i], t = targets[i];
        const float bce = fmaxf(p, 0.f) - p * t + log1pf(expf(-fabsf(p)));
        const float pt = expf(-bce);
        const float om = 1.f - pt;
        float fv = 0.25f * om * om * bce;
        #pragma unroll
        for (int off = 32; off > 0; off >>= 1) fv += __shfl_down(fv, off);
        if (lane == 0) f_part[chunk * 4 + w4] = fv;
    } else {
        // ---- graph: 4 quad-parallel chunks (v3-verified) ----
        const int cq = tid >> 8;
        const int w4 = (tid >> 6) & 3;
        const int chunk = (bx - NPAIRB - NPREPB - NFOCALB) * 4 + cq;
        float ga = 0.f;
        #pragma unroll
        for (int it = 0; it < 8; ++it) {
            const int r = chunk * 4 + w4 + it * 1024;
            if (r < N_PTS - 1) {
                const float2 a = *reinterpret_cast<const float2*>(gfeat + r * DIM + lane * 2);
                const float2 bb = *reinterpret_cast<const float2*>(gfeat + (r + 1) * DIM + lane * 2);
                const float dx = bb.x - a.x, dy = bb.y - a.y;
                float s = dx * dx + dy * dy;
                #pragma unroll
                for (int off = 32; off > 0; off >>= 1) s += __shfl_down(s, off);
                if (lane == 0) ga += sqrtf(s);
            }
        }
        if (lane == 0) g_part[chunk * 4 + w4] = ga;
    }
}

// ================= launch 2: finalize (1 block, verified v3/v5) ================
__global__ __launch_bounds__(256) void finalize_kernel(const float* __restrict__ c_part,
                                                       const float* __restrict__ f_part,
                                                       const float* __restrict__ g_part,
                                                       const float* __restrict__ vpart,
                                                       const float* __restrict__ spart,
                                                       float* __restrict__ out) {
    __shared__ double sC[4], sF[4], sG[4], sV[4], sST[4], sS1[4], sN1[4];
    const int tid = threadIdx.x;
    const int w = tid >> 6, lane = tid & 63;

    double c = 0.0;
    for (int i = tid; i < NPAIRB * 16; i += 256) c += (double)c_part[i];
    double f = (tid < 128) ? (double)f_part[tid] : 0.0;
    double g = 0.0;
    for (int i = tid; i < 1024; i += 256) g += (double)g_part[i];

    float V = 0.f;
    #pragma unroll 8
    for (int b2 = 0; b2 < 128; ++b2) V += vpart[b2 * 256 + tid];
    double vsq = (double)V * (double)V;   // tid<128: class0 dims; else class1

    double st = 0.0, s1 = 0.0, n1 = 0.0;
    if (tid < 128) {
        const float4 s = *reinterpret_cast<const float4*>(spart + tid * 4);
        st = s.x; s1 = s.y; n1 = s.z;
    }
    #pragma unroll
    for (int off = 32; off > 0; off >>= 1) {
        c += __shfl_down(c, off);
        f += __shfl_down(f, off);
        g += __shfl_down(g, off);
        vsq += __shfl_down(vsq, off);
        st += __shfl_down(st, off);
        s1 += __shfl_down(s1, off);
        n1 += __shfl_down(n1, off);
    }
    if (lane == 0) {
        sC[w] = c; sF[w] = f; sG[w] = g; sV[w] = vsq;
        sST[w] = st; sS1[w] = s1; sN1[w] = n1;
    }
    __syncthreads();
    if (tid == 0) {
        const double cs = sC[0] + sC[1] + sC[2] + sC[3];
        const double fs = sF[0] + sF[1] + sF[2] + sF[3];
        const double gs = sG[0] + sG[1] + sG[2] + sG[3];
        const double v0sq = sV[0] + sV[1];           // waves 0,1 = class0
        const double v1sq = sV[2] + sV[3];
        const double stot = sST[0] + sST[1] + sST[2] + sST[3];
        const double s1s  = sS1[0] + sS1[1] + sS1[2] + sS1[3];
        const double n1s  = sN1[0] + sN1[1] + sN1[2] + sN1[3];
        const double n0s = (double)N_PTS - n1s;
        const double s0s = stot - s1s;
        const double same = 2.0 * (n0s * s0s - v0sq) + 2.0 * (n1s * s1s - v1sq);
        out[0] = (float)((cs + same) / ((double)N_PTS * (double)N_PTS)
                         + fs / (double)N_PTS
                         + 0.1 * (gs / (double)(N_PTS - 1)));
    }
}

extern "C" void kernel_launch(void* const* d_in, const int* in_sizes, int n_in,
                              void* d_out, int out_size, void* d_ws, size_t ws_size,
                              hipStream_t stream) {
    const float* preds    = (const float*)d_in[0];
    const float* targets  = (const float*)d_in[1];
    const float* features = (const float*)d_in[2];
    const float* gfeat    = (const float*)d_in[3];
    char* ws = (char*)d_ws;
    float* vpart  = (float*)(ws + VPART_OFF);
    float* spart  = (float*)(ws + SPART_OFF);
    float* c_part = (float*)(ws + CPART_OFF);
    float* f_part = (float*)(ws + FPART_OFF);
    float* g_part = (float*)(ws + GPART_OFF);
    float* out = (float*)d_out;

    main_kernel<<<NMAIN, 1024, 0, stream>>>(features, preds, targets, gfeat,
                                            vpart, spart, c_part, f_part, g_part);
    finalize_kernel<<<1, 256, 0, stream>>>(c_part, f_part, g_part, vpart, spart, out);
}